// Round 8
// baseline (53135.107 us; speedup 1.0000x reference)
//
#include <hip/hip_runtime.h>
#include <hip/hip_bf16.h>

typedef __attribute__((ext_vector_type(8))) short short8;
typedef __attribute__((ext_vector_type(4))) float f32x4;
typedef __attribute__((ext_vector_type(4))) unsigned u32x4;

#define T_STEPS 2048
#define HDIM 512
#define SLICE_T (64 * 512)      // elems per time slice

#define MFMA16 __builtin_amdgcn_mfma_f32_16x16x32_bf16

static __device__ __forceinline__ short f2bf(float f) {
    __hip_bfloat16 h = __float2bfloat16(f);
    return __builtin_bit_cast(short, h);
}
static __device__ __forceinline__ float bf2f(short s) {
    unsigned u = ((unsigned)(unsigned short)s) << 16;
    return __builtin_bit_cast(float, u);
}
// pack f32 -> u32 {bf16hi | bf16lo<<16}, lo = bf16(x - hi); exact for +-1.0
static __device__ __forceinline__ unsigned packsplit(float f) {
    short hi = f2bf(f);
    short lo = f2bf(f - bf2f(hi));
    return (unsigned)(unsigned short)hi | ((unsigned)(unsigned short)lo << 16);
}
static __device__ __forceinline__ void unpack2w(unsigned p0, unsigned p1,
                                                unsigned& hw, unsigned& lw) {
    hw = __builtin_amdgcn_perm(p1, p0, 0x05040100u);
    lw = __builtin_amdgcn_perm(p1, p0, 0x07060302u);
}
union S8U { short8 s8; unsigned u[4]; };
static __device__ __forceinline__ void build8v(u32x4 a, u32x4 b, short8& hi, short8& lo) {
    S8U H, L;
    unpack2w(a[0], a[1], H.u[0], L.u[0]);
    unpack2w(a[2], a[3], H.u[1], L.u[1]);
    unpack2w(b[0], b[1], H.u[2], L.u[2]);
    unpack2w(b[2], b[3], H.u[3], L.u[3]);
    hi = H.s8; lo = L.s8;
}
// guarded fast tanh: exact +-1.0 at saturation, ~1e-6 mid-range error
static __device__ __forceinline__ float fast_tanh(float x) {
    const float xc = fminf(15.0f, fmaxf(-15.0f, x));
    const float e = __expf(2.0f * xc);
    return (e - 1.0f) / (e + 1.0f);
}

// ---------------- Phase 1: xp(t) = input[t] @ Wx + bias -> out[t+1] --------
// (unchanged from R6 — measured ~1.0 ms)
__global__ __launch_bounds__(256, 2) void rnn_xproj(
    const float* __restrict__ input, const float* __restrict__ weight,
    const float* __restrict__ bias, float* __restrict__ out)
{
    __shared__ unsigned alds[64 * 128];
    __shared__ unsigned wlds[64 * 128];
    const int tid = threadIdx.x, lane = tid & 63, wv = tid >> 6;
    const int t = blockIdx.x >> 3, ct = blockIdx.x & 7;
    const int r16 = lane & 15, kg = lane >> 4, koff = kg * 8;
    const int colt = wv * 16 + r16;
    const int gcol = ct * 64 + colt;
    const float bv = bias[gcol];

    f32x4 acc[4][3];
#pragma unroll
    for (int mt = 0; mt < 4; ++mt) {
        acc[mt][0] = (f32x4){bv, bv, bv, bv};
        acc[mt][1] = (f32x4){0, 0, 0, 0};
        acc[mt][2] = (f32x4){0, 0, 0, 0};
    }

    for (int kq = 0; kq < 4; ++kq) {
        __syncthreads();
        for (int f = tid; f < 64 * 32; f += 256) {
            const int row = f >> 5, sg = f & 31;
            f32x4 v = *(const f32x4*)(input + (size_t)t * SLICE_T + row * HDIM + kq * 128 + sg * 4);
            const unsigned idx = ((unsigned)(row * 128 + sg * 4)) ^ (((unsigned)(row & 7)) << 2);
            u32x4 pk = {packsplit(v[0]), packsplit(v[1]), packsplit(v[2]), packsplit(v[3])};
            *(u32x4*)(&alds[idx]) = pk;
        }
        for (int f = tid; f < 128 * 16; f += 256) {
            const int k = f >> 4, cs = f & 15;
            f32x4 v = *(const f32x4*)(weight + (size_t)(kq * 128 + k) * HDIM + ct * 64 + cs * 4);
#pragma unroll
            for (int j = 0; j < 4; ++j) {
                const int c = cs * 4 + j;
                wlds[((unsigned)(c * 128 + k)) ^ (((unsigned)(c & 7)) << 2)] = packsplit(v[j]);
            }
        }
        __syncthreads();
#pragma unroll
        for (int c2 = 0; c2 < 4; ++c2) {
            const int kp = c2 * 32 + koff;
            const unsigned bi = (unsigned)(colt * 128 + kp), bx = ((unsigned)(colt & 7)) << 2;
            u32x4 qb0 = *(const u32x4*)&wlds[bi ^ bx];
            u32x4 qb1 = *(const u32x4*)&wlds[(bi + 4) ^ bx];
            short8 bhi, blo; build8v(qb0, qb1, bhi, blo);
#pragma unroll
            for (int mt = 0; mt < 4; ++mt) {
                const int row = mt * 16 + r16;
                const unsigned ai = (unsigned)(row * 128 + kp), ax = ((unsigned)(row & 7)) << 2;
                u32x4 qa0 = *(const u32x4*)&alds[ai ^ ax];
                u32x4 qa1 = *(const u32x4*)&alds[(ai + 4) ^ ax];
                short8 ahi, alo; build8v(qa0, qa1, ahi, alo);
                acc[mt][0] = MFMA16(ahi, bhi, acc[mt][0], 0, 0, 0);
                acc[mt][1] = MFMA16(alo, bhi, acc[mt][1], 0, 0, 0);
                acc[mt][2] = MFMA16(ahi, blo, acc[mt][2], 0, 0, 0);
            }
        }
    }
    float* ob = out + (size_t)(t + 1) * SLICE_T;
#pragma unroll
    for (int mt = 0; mt < 4; ++mt)
#pragma unroll
        for (int r = 0; r < 4; ++r)
            ob[(mt * 16 + kg * 4 + r) * HDIM + gcol] =
                acc[mt][0][r] + acc[mt][1][r] + acc[mt][2][r];
}

// ---------------- Phase 2: single-CU-per-group scan, LDS-only exchange -----
// 4 WGs x 1024 threads (16 waves). Each WG owns 16 batch rows (M=16, no
// padded waste) and holds the ENTIRE Wh in the CU's register file: each
// wave keeps its 32 columns as hi/lo short8 B-fragments (256 VGPRs; 512
// available at 1 WG/CU per launch_bounds(1024,1)). h_t lives in a
// double-buffered XOR-swizzled LDS buffer; the step handshake is ONE
// __syncthreads. Zero cross-WG communication -> no IC latency, no
// coherence protocol, no hang risk.
__global__ __launch_bounds__(1024, 1) void rnn_scan(
    const float* __restrict__ weight, const float* __restrict__ init_h,
    float* __restrict__ out)
{
    __shared__ unsigned hbuf[2][16 * HDIM];   // packed {hi|lo} h, 64 KB

    const int tid = threadIdx.x, lane = tid & 63, wv = tid >> 6;  // wv 0..15
    const int g = blockIdx.x;                 // batch rows 16g..16g+15
    const int r16 = lane & 15, kg = lane >> 4, koff = kg * 8;
    const int cb0 = wv * 32;                  // this wave's 32-col base

    // ---- one-time: Wh B-fragments into registers (2 col-tiles x 16 kb) ----
    short8 wh_hi[2][16], wh_lo[2][16];
#pragma unroll
    for (int ct = 0; ct < 2; ++ct) {
        const int col = cb0 + ct * 16 + r16;
#pragma unroll
        for (int c = 0; c < 16; ++c) {
            short8 hh, hl;
#pragma unroll
            for (int j = 0; j < 8; ++j) {
                const float w = weight[(size_t)(HDIM + c * 32 + koff + j) * HDIM + col];
                short a = f2bf(w); hh[j] = a; hl[j] = f2bf(w - bf2f(a));
            }
            wh_hi[ct][c] = hh; wh_lo[ct][c] = hl;
        }
    }

    // ---- init: h0 (broadcast init_h) into hbuf[0] + out[0] rows ----
    for (int i = tid; i < 16 * HDIM; i += 1024) {
        const int row = i >> 9, col = i & 511;
        const float v = init_h[col];
        hbuf[0][(row << 9) + (col ^ ((row & 7) << 2))] = packsplit(v);
        out[(size_t)(g * 16 + row) * HDIM + col] = v;
    }
    __syncthreads();

    for (int t = 0; t < T_STEPS; ++t) {
        const unsigned* hc = hbuf[t & 1];
        unsigned* hn = hbuf[(t + 1) & 1];

        // prefetch xp(t) from out[t+1] (phase-1 output; overwritten below,
        // ordered by the load->tanh->store data dependency per lane)
        const float* xb = out + (size_t)(t + 1) * SLICE_T + (size_t)(g * 16) * HDIM;
        float xp[2][4];
#pragma unroll
        for (int ct = 0; ct < 2; ++ct)
#pragma unroll
            for (int r = 0; r < 4; ++r)
                xp[ct][r] = xb[(size_t)(kg * 4 + r) * HDIM + cb0 + ct * 16 + r16];

        // preact = xp + h_t @ Wh  (A from swizzled LDS, B from registers)
        f32x4 acc[2][3];
#pragma unroll
        for (int ct = 0; ct < 2; ++ct) {
            acc[ct][0] = (f32x4){0, 0, 0, 0};
            acc[ct][1] = (f32x4){0, 0, 0, 0};
            acc[ct][2] = (f32x4){0, 0, 0, 0};
        }
        const unsigned xr = ((unsigned)(r16 & 7)) << 2;
        const unsigned rbase = (unsigned)r16 << 9;
#pragma unroll
        for (int c = 0; c < 16; ++c) {
            const unsigned cb = (unsigned)(c * 32 + koff);
            u32x4 a0 = *(const u32x4*)&hc[rbase + (cb ^ xr)];
            u32x4 a1 = *(const u32x4*)&hc[rbase + ((cb + 4) ^ xr)];
            short8 ahi, alo; build8v(a0, a1, ahi, alo);
#pragma unroll
            for (int ct = 0; ct < 2; ++ct) {
                acc[ct][0] = MFMA16(ahi, wh_hi[ct][c], acc[ct][0], 0, 0, 0);
                acc[ct][1] = MFMA16(alo, wh_hi[ct][c], acc[ct][1], 0, 0, 0);
                acc[ct][2] = MFMA16(ahi, wh_lo[ct][c], acc[ct][2], 0, 0, 0);
            }
        }

        // h_{t+1} = tanh(preact): LDS (packed, swizzled) + global f32
        float* ob = out + (size_t)(t + 1) * SLICE_T + (size_t)(g * 16) * HDIM;
#pragma unroll
        for (int ct = 0; ct < 2; ++ct) {
            const int col = cb0 + ct * 16 + r16;
#pragma unroll
            for (int r = 0; r < 4; ++r) {
                const int row = kg * 4 + r;
                const float h = fast_tanh(acc[ct][0][r] + acc[ct][1][r] +
                                          acc[ct][2][r] + xp[ct][r]);
                hn[(row << 9) + (col ^ ((row & 7) << 2))] = packsplit(h);
                __builtin_nontemporal_store(h, ob + (size_t)row * HDIM + col);
            }
        }
        __syncthreads();   // h_{t+1} complete before next step reads it
    }
}

extern "C" void kernel_launch(void* const* d_in, const int* in_sizes, int n_in,
                              void* d_out, int out_size, void* d_ws, size_t ws_size,
                              hipStream_t stream) {
    const float* input  = (const float*)d_in[0];
    const float* weight = (const float*)d_in[1];
    const float* biasp  = (const float*)d_in[2];
    const float* inith  = (const float*)d_in[3];
    float* out = (float*)d_out;

    rnn_xproj<<<dim3(T_STEPS * 8), dim3(256), 0, stream>>>(input, weight, biasp, out);
    rnn_scan<<<dim3(4), dim3(1024), 0, stream>>>(weight, inith, out);
}

// Round 9
// 15313.492 us; speedup vs baseline: 3.4698x; 3.4698x over previous
//
#include <hip/hip_runtime.h>
#include <hip/hip_bf16.h>

typedef __attribute__((ext_vector_type(8))) short short8;
typedef __attribute__((ext_vector_type(4))) float f32x4;
typedef __attribute__((ext_vector_type(4))) unsigned u32x4;

#define T_STEPS 2048
#define HDIM 512
#define SLICE_T (64 * 512)      // elems per time slice
#define NGROUP 8                // batch groups (8 rows each)
#define NSLICE 16               // col slices (32 cols each)
#define CAN_OFF 0               // canaries: [128] 64B lines (8 KB)
#define RING_OFF 16384          // ring: [2][64][512] packed u32 (1 MB)
#define SPIN_CAP 100000         // per-step poll budget; dead-mode, no hang

#define MFMA16 __builtin_amdgcn_mfma_f32_16x16x32_bf16
#define ALOAD(p)   __hip_atomic_load((p), __ATOMIC_RELAXED, __HIP_MEMORY_SCOPE_AGENT)
#define ASWAP(p,v) (void)__hip_atomic_exchange((p), (v), __ATOMIC_RELAXED, __HIP_MEMORY_SCOPE_AGENT)

static __device__ __forceinline__ short f2bf(float f) {
    __hip_bfloat16 h = __float2bfloat16(f);
    return __builtin_bit_cast(short, h);
}
static __device__ __forceinline__ float bf2f(short s) {
    unsigned u = ((unsigned)(unsigned short)s) << 16;
    return __builtin_bit_cast(float, u);
}
// pack f32 -> u32 {bf16hi | bf16lo<<16}, lo = bf16(x - hi); exact for +-1.0
static __device__ __forceinline__ unsigned packsplit(float f) {
    short hi = f2bf(f);
    short lo = f2bf(f - bf2f(hi));
    return (unsigned)(unsigned short)hi | ((unsigned)(unsigned short)lo << 16);
}
// epoch tag in bit16 (lo-bf16 LSB, ~2^-17 abs error -> negligible, R7-proven)
static __device__ __forceinline__ unsigned tagset(unsigned pk, unsigned e) {
    return (pk & ~(1u << 16)) | (e << 16);
}
static __device__ __forceinline__ unsigned tagbad(unsigned long long q, unsigned e) {
    return (((unsigned)(q >> 16) ^ e) & 1u) | (((unsigned)(q >> 48) ^ e) & 1u);
}
static __device__ __forceinline__ void unpack2w(unsigned p0, unsigned p1,
                                                unsigned& hw, unsigned& lw) {
    hw = __builtin_amdgcn_perm(p1, p0, 0x05040100u);
    lw = __builtin_amdgcn_perm(p1, p0, 0x07060302u);
}
union S8U { short8 s8; unsigned u[4]; };
static __device__ __forceinline__ void build8v(u32x4 a, u32x4 b, short8& hi, short8& lo) {
    S8U H, L;
    unpack2w(a[0], a[1], H.u[0], L.u[0]);
    unpack2w(a[2], a[3], H.u[1], L.u[1]);
    unpack2w(b[0], b[1], H.u[2], L.u[2]);
    unpack2w(b[2], b[3], H.u[3], L.u[3]);
    hi = H.s8; lo = L.s8;
}
static __device__ __forceinline__ void split8v(f32x4 u, f32x4 v, short8& hi, short8& lo) {
#pragma unroll
    for (int j = 0; j < 4; ++j) { short h = f2bf(u[j]); hi[j] = h; lo[j] = f2bf(u[j] - bf2f(h)); }
#pragma unroll
    for (int j = 0; j < 4; ++j) { short h = f2bf(v[j]); hi[4+j] = h; lo[4+j] = f2bf(v[j] - bf2f(h)); }
}
// guarded fast tanh: exact +-1.0 at saturation
static __device__ __forceinline__ float fast_tanh(float x) {
    const float xc = fminf(15.0f, fmaxf(-15.0f, x));
    const float e = __expf(2.0f * xc);
    return (e - 1.0f) / (e + 1.0f);
}

// ---------------- Phase 1: xp(t) = input[t] @ Wx + bias -> out[t+1] --------
// (unchanged from R6 — measured ~1.0 ms)
__global__ __launch_bounds__(256, 2) void rnn_xproj(
    const float* __restrict__ input, const float* __restrict__ weight,
    const float* __restrict__ bias, float* __restrict__ out)
{
    __shared__ unsigned alds[64 * 128];
    __shared__ unsigned wlds[64 * 128];
    const int tid = threadIdx.x, lane = tid & 63, wv = tid >> 6;
    const int t = blockIdx.x >> 3, ct = blockIdx.x & 7;
    const int r16 = lane & 15, kg = lane >> 4, koff = kg * 8;
    const int colt = wv * 16 + r16;
    const int gcol = ct * 64 + colt;
    const float bv = bias[gcol];

    f32x4 acc[4][3];
#pragma unroll
    for (int mt = 0; mt < 4; ++mt) {
        acc[mt][0] = (f32x4){bv, bv, bv, bv};
        acc[mt][1] = (f32x4){0, 0, 0, 0};
        acc[mt][2] = (f32x4){0, 0, 0, 0};
    }

    for (int kq = 0; kq < 4; ++kq) {
        __syncthreads();
        for (int f = tid; f < 64 * 32; f += 256) {
            const int row = f >> 5, sg = f & 31;
            f32x4 v = *(const f32x4*)(input + (size_t)t * SLICE_T + row * HDIM + kq * 128 + sg * 4);
            const unsigned idx = ((unsigned)(row * 128 + sg * 4)) ^ (((unsigned)(row & 7)) << 2);
            u32x4 pk = {packsplit(v[0]), packsplit(v[1]), packsplit(v[2]), packsplit(v[3])};
            *(u32x4*)(&alds[idx]) = pk;
        }
        for (int f = tid; f < 128 * 16; f += 256) {
            const int k = f >> 4, cs = f & 15;
            f32x4 v = *(const f32x4*)(weight + (size_t)(kq * 128 + k) * HDIM + ct * 64 + cs * 4);
#pragma unroll
            for (int j = 0; j < 4; ++j) {
                const int c = cs * 4 + j;
                wlds[((unsigned)(c * 128 + k)) ^ (((unsigned)(c & 7)) << 2)] = packsplit(v[j]);
            }
        }
        __syncthreads();
#pragma unroll
        for (int c2 = 0; c2 < 4; ++c2) {
            const int kp = c2 * 32 + koff;
            const unsigned bi = (unsigned)(colt * 128 + kp), bx = ((unsigned)(colt & 7)) << 2;
            u32x4 qb0 = *(const u32x4*)&wlds[bi ^ bx];
            u32x4 qb1 = *(const u32x4*)&wlds[(bi + 4) ^ bx];
            short8 bhi, blo; build8v(qb0, qb1, bhi, blo);
#pragma unroll
            for (int mt = 0; mt < 4; ++mt) {
                const int row = mt * 16 + r16;
                const unsigned ai = (unsigned)(row * 128 + kp), ax = ((unsigned)(row & 7)) << 2;
                u32x4 qa0 = *(const u32x4*)&alds[ai ^ ax];
                u32x4 qa1 = *(const u32x4*)&alds[(ai + 4) ^ ax];
                short8 ahi, alo; build8v(qa0, qa1, ahi, alo);
                acc[mt][0] = MFMA16(ahi, bhi, acc[mt][0], 0, 0, 0);
                acc[mt][1] = MFMA16(alo, bhi, acc[mt][1], 0, 0, 0);
                acc[mt][2] = MFMA16(ahi, blo, acc[mt][2], 0, 0, 0);
            }
        }
    }
    float* ob = out + (size_t)(t + 1) * SLICE_T;
#pragma unroll
    for (int mt = 0; mt < 4; ++mt)
#pragma unroll
        for (int r = 0; r < 4; ++r)
            ob[(mt * 16 + kg * 4 + r) * HDIM + gcol] =
                acc[mt][0][r] + acc[mt][1][r] + acc[mt][2][r];
}

// ---------------- Phase 2: persistent scan, speculative tagged exchange ----
// 128 WGs = 8 groups x 16 slices, ONE 64-lane wave each (no intra-WG sync).
// Wh slice (512 k x 32 cols, packed hi/lo) in 64 KB LDS, each lane reading
// back only its own fragment slot (LDS as per-lane register extension).
// Per step: speculative tagged payload loads were issued in the previous
// step's tail; if all epoch tags match, consume immediately (zero sync
// hops). Otherwise fall back to R6's proven narrow canary poll, then ONE
// guaranteed-fresh reload. Producer: tagged RMW swaps -> vmcnt(0) ->
// canary swap. Tag soundness: at read time a slot holds h_t or h_{t-2}
// only (skew bounded by the canary/tag gating), so 1 epoch bit suffices.
__global__ __launch_bounds__(64, 1) void rnn_scan(
    const float* __restrict__ weight, const float* __restrict__ init_h,
    float* __restrict__ out, unsigned char* __restrict__ ws)
{
    __shared__ u32x4 whf[16][2][2][64];   // [kblock][coltile][half][lane], 64 KB
    unsigned* canary = (unsigned*)(ws + CAN_OFF);   // [128] 64B lines
    unsigned* ring   = (unsigned*)(ws + RING_OFF);  // [2][64][512] packed u32

    const int lane = threadIdx.x;
    const int g = blockIdx.x & 7, s = blockIdx.x >> 3;
    const int r16 = lane & 15, kg = lane >> 4, koff = kg * 8;
    const int brow = g * 8 + (r16 & 7);

    // ---- one-time: Wh fragments -> LDS (own-lane slots) ----
#pragma unroll
    for (int ct = 0; ct < 2; ++ct) {
        const int col = s * 32 + ct * 16 + r16;
#pragma unroll
        for (int c = 0; c < 16; ++c) {
            unsigned p[8];
#pragma unroll
            for (int j = 0; j < 8; ++j)
                p[j] = packsplit(weight[(size_t)(HDIM + c * 32 + koff + j) * HDIM + col]);
            whf[c][ct][0][lane] = (u32x4){p[0], p[1], p[2], p[3]};
            whf[c][ct][1][lane] = (u32x4){p[4], p[5], p[6], p[7]};
        }
    }
    // ---- out[0] = broadcast init_h (this wave's 8 rows x 32 cols) ----
    for (int i = lane; i < 8 * 32; i += 64) {
        const int row = i >> 5, cc = i & 31;
        out[(size_t)(g * 8 + row) * HDIM + s * 32 + cc] = init_h[s * 32 + cc];
    }
    __syncthreads();

    unsigned long long q[16][4];   // speculative payload (128 VGPRs)
    float xp[2][4];
    // prologue: xp(0) from out[1]
    {
        const float* xb = out + (size_t)1 * SLICE_T + (size_t)(g * 8) * HDIM;
#pragma unroll
        for (int ct = 0; ct < 2; ++ct)
#pragma unroll
            for (int r = 0; r < 4; ++r)
                xp[ct][r] = xb[(size_t)((kg & 1) * 4 + r) * HDIM + s * 32 + ct * 16 + r16];
    }

    bool dead = false;
    for (int t = 0; t < T_STEPS; ++t) {
        const bool has_next = (t + 1 < T_STEPS);
        const unsigned er = ((unsigned)t >> 1) & 1u;
        const unsigned ew = ((unsigned)(t + 1) >> 1) & 1u;

        f32x4 acc[2][3];
#pragma unroll
        for (int ct = 0; ct < 2; ++ct) {
            acc[ct][0] = (f32x4){0, 0, 0, 0};
            acc[ct][1] = (f32x4){0, 0, 0, 0};
            acc[ct][2] = (f32x4){0, 0, 0, 0};
        }

        if (t == 0) {
#pragma unroll
            for (int c = 0; c < 16; ++c) {
                f32x4 u = *(const f32x4*)(init_h + c * 32 + koff);
                f32x4 v = *(const f32x4*)(init_h + c * 32 + koff + 4);
                short8 ahi, alo; split8v(u, v, ahi, alo);
#pragma unroll
                for (int ct = 0; ct < 2; ++ct) {
                    short8 bhi, blo; build8v(whf[c][ct][0][lane], whf[c][ct][1][lane], bhi, blo);
                    acc[ct][0] = MFMA16(ahi, bhi, acc[ct][0], 0, 0, 0);
                    acc[ct][1] = MFMA16(alo, bhi, acc[ct][1], 0, 0, 0);
                    acc[ct][2] = MFMA16(ahi, blo, acc[ct][2], 0, 0, 0);
                }
            }
        } else {
            // ---- validate speculative loads (issued in previous tail) ----
            unsigned bad = 0;
#pragma unroll
            for (int c = 0; c < 16; ++c)
                bad |= tagbad(q[c][0], er) | tagbad(q[c][1], er)
                     | tagbad(q[c][2], er) | tagbad(q[c][3], er);
            if (!dead && __any((int)bad)) {
                // narrow canary poll (R6-proven), bounded
                int budget = SPIN_CAP, to = 0;
                for (;;) {
                    unsigned cv = 0xffffffffu;
                    if (lane < NSLICE) cv = ALOAD(&canary[(g * NSLICE + lane) * 16]);
                    if (__all((int)(cv >= (unsigned)t))) break;
                    if (--budget <= 0) { to = 1; break; }
                }
                if (to) dead = true;
                else {
                    // ONE guaranteed-fresh reload (canary => data at IC)
                    const unsigned* rb = ring + (t & 1) * SLICE_T + brow * HDIM;
#pragma unroll
                    for (int c = 0; c < 16; ++c) {
                        const unsigned* p = rb + c * 32 + koff;
                        q[c][0] = ALOAD((const unsigned long long*)(p + 0));
                        q[c][1] = ALOAD((const unsigned long long*)(p + 2));
                        q[c][2] = ALOAD((const unsigned long long*)(p + 4));
                        q[c][3] = ALOAD((const unsigned long long*)(p + 6));
                    }
                }
            }
            // ---- consume ----
#pragma unroll
            for (int c = 0; c < 16; ++c) {
                S8U hh, hl;
                unpack2w((unsigned)q[c][0], (unsigned)(q[c][0] >> 32), hh.u[0], hl.u[0]);
                unpack2w((unsigned)q[c][1], (unsigned)(q[c][1] >> 32), hh.u[1], hl.u[1]);
                unpack2w((unsigned)q[c][2], (unsigned)(q[c][2] >> 32), hh.u[2], hl.u[2]);
                unpack2w((unsigned)q[c][3], (unsigned)(q[c][3] >> 32), hh.u[3], hl.u[3]);
#pragma unroll
                for (int ct = 0; ct < 2; ++ct) {
                    short8 bhi, blo; build8v(whf[c][ct][0][lane], whf[c][ct][1][lane], bhi, blo);
                    acc[ct][0] = MFMA16(hh.s8, bhi, acc[ct][0], 0, 0, 0);
                    acc[ct][1] = MFMA16(hl.s8, bhi, acc[ct][1], 0, 0, 0);
                    acc[ct][2] = MFMA16(hh.s8, blo, acc[ct][2], 0, 0, 0);
                }
            }
        }

        float hn[2][4];
#pragma unroll
        for (int ct = 0; ct < 2; ++ct)
#pragma unroll
            for (int r = 0; r < 4; ++r)
                hn[ct][r] = fast_tanh(acc[ct][0][r] + acc[ct][1][r] +
                                      acc[ct][2][r] + xp[ct][r]);

        // ---- post h_{t+1}: tagged RMW swaps, drain, canary ----
        if (kg < 2 && has_next) {
#pragma unroll
            for (int ct = 0; ct < 2; ++ct) {
                unsigned* wb = ring + ((t + 1) & 1) * SLICE_T
                                    + (size_t)(g * 8 + kg * 4) * HDIM
                                    + s * 32 + ct * 16 + r16;
#pragma unroll
                for (int r = 0; r < 4; ++r)
                    ASWAP(&wb[(size_t)r * HDIM], tagset(packsplit(hn[ct][r]), ew));
            }
        }
        asm volatile("s_waitcnt vmcnt(0)" ::: "memory");
        if (lane == 0 && has_next)
            ASWAP(&canary[(g * NSLICE + s) * 16], (unsigned)(t + 1));

        // ---- tail: speculative issue for step t+1 (overlaps peers' posts) --
        if (has_next) {
            const unsigned* rb = ring + ((t + 1) & 1) * SLICE_T + brow * HDIM;
#pragma unroll
            for (int c = 0; c < 16; ++c) {
                const unsigned* p = rb + c * 32 + koff;
                q[c][0] = ALOAD((const unsigned long long*)(p + 0));
                q[c][1] = ALOAD((const unsigned long long*)(p + 2));
                q[c][2] = ALOAD((const unsigned long long*)(p + 4));
                q[c][3] = ALOAD((const unsigned long long*)(p + 6));
            }
            const float* xb = out + (size_t)(t + 2) * SLICE_T + (size_t)(g * 8) * HDIM;
#pragma unroll
            for (int ct = 0; ct < 2; ++ct)
#pragma unroll
                for (int r = 0; r < 4; ++r)
                    xp[ct][r] = xb[(size_t)((kg & 1) * 4 + r) * HDIM + s * 32 + ct * 16 + r16];
        }
        // ---- off critical path: f32 h to out[t+1] ----
        if (kg < 2) {
#pragma unroll
            for (int ct = 0; ct < 2; ++ct) {
                float* op = out + (size_t)(t + 1) * SLICE_T
                                + (size_t)(g * 8 + kg * 4) * HDIM + s * 32 + ct * 16 + r16;
#pragma unroll
                for (int r = 0; r < 4; ++r)
                    __builtin_nontemporal_store(hn[ct][r], op + (size_t)r * HDIM);
            }
        }
    }
}

extern "C" void kernel_launch(void* const* d_in, const int* in_sizes, int n_in,
                              void* d_out, int out_size, void* d_ws, size_t ws_size,
                              hipStream_t stream) {
    const float* input  = (const float*)d_in[0];
    const float* weight = (const float*)d_in[1];
    const float* biasp  = (const float*)d_in[2];
    const float* inith  = (const float*)d_in[3];
    float* out = (float*)d_out;

    // canaries zero; ring slot0 tag=0 (first reader t=2 expects 1), slot1
    // tag=1 (first reader t=1 expects 0). Re-done every call -> graph-safe.
    hipMemsetAsync(d_ws, 0x00, RING_OFF, stream);
    hipMemsetAsync((char*)d_ws + RING_OFF, 0x00, SLICE_T * 4, stream);
    hipMemsetAsync((char*)d_ws + RING_OFF + SLICE_T * 4, 0xFF, SLICE_T * 4, stream);

    rnn_xproj<<<dim3(T_STEPS * 8), dim3(256), 0, stream>>>(input, weight, biasp, out);
    rnn_scan<<<dim3(NGROUP * NSLICE), dim3(64), 0, stream>>>(
        weight, inith, out, (unsigned char*)d_ws);
}

// Round 12
// 13929.521 us; speedup vs baseline: 3.8146x; 1.0994x over previous
//
#include <hip/hip_runtime.h>
#include <hip/hip_bf16.h>

typedef __attribute__((ext_vector_type(8))) short short8;
typedef __attribute__((ext_vector_type(4))) float f32x4;
typedef __attribute__((ext_vector_type(4))) unsigned u32x4;

#define T_STEPS 2048
#define HDIM 512
#define SLICE_T (64 * 512)      // elems per time slice
#define NGROUP 8                // batch groups (8 rows each)
#define NSLICE 16               // col slices (32 cols each)
#define CAN_OFF 0               // canaries: [128] 128B lines (16 KB)
#define COLSUM_OFF 16384        // colsum f32[512] (2 KB)
#define FLAG_OFF 32768          // flagg u32[2048][8] (64 KB)
#define RING_OFF 131072         // ring [2][64][512] packed u32 (256 KB); ws>=384KB (R3-proven)
#define SPIN_CAP 200000         // bounded spin; dead-mode, no hang
#define SAT_MARGIN 9.5f         // > 9.01 (tanhf==1.0f cutoff) + xp-error margin

#define MFMA16 __builtin_amdgcn_mfma_f32_16x16x32_bf16
#define ALOAD(p)   __hip_atomic_load((p), __ATOMIC_RELAXED, __HIP_MEMORY_SCOPE_AGENT)
#define ASWAP(p,v) (void)__hip_atomic_exchange((p), (v), __ATOMIC_RELAXED, __HIP_MEMORY_SCOPE_AGENT)

static __device__ __forceinline__ short f2bf(float f) {
    __hip_bfloat16 h = __float2bfloat16(f);
    return __builtin_bit_cast(short, h);
}
static __device__ __forceinline__ float bf2f(short s) {
    unsigned u = ((unsigned)(unsigned short)s) << 16;
    return __builtin_bit_cast(float, u);
}
// pack f32 -> u32 {bf16hi | bf16lo<<16}, lo = bf16(x - hi); exact for +-1.0
static __device__ __forceinline__ unsigned packsplit(float f) {
    short hi = f2bf(f);
    short lo = f2bf(f - bf2f(hi));
    return (unsigned)(unsigned short)hi | ((unsigned)(unsigned short)lo << 16);
}
static __device__ __forceinline__ void unpack2w(unsigned p0, unsigned p1,
                                                unsigned& hw, unsigned& lw) {
    hw = __builtin_amdgcn_perm(p1, p0, 0x05040100u);
    lw = __builtin_amdgcn_perm(p1, p0, 0x07060302u);
}
union S8U { short8 s8; unsigned u[4]; };
static __device__ __forceinline__ void build8v(u32x4 a, u32x4 b, short8& hi, short8& lo) {
    S8U H, L;
    unpack2w(a[0], a[1], H.u[0], L.u[0]);
    unpack2w(a[2], a[3], H.u[1], L.u[1]);
    unpack2w(b[0], b[1], H.u[2], L.u[2]);
    unpack2w(b[2], b[3], H.u[3], L.u[3]);
    hi = H.s8; lo = L.s8;
}
static __device__ __forceinline__ void split8v(f32x4 u, f32x4 v, short8& hi, short8& lo) {
#pragma unroll
    for (int j = 0; j < 4; ++j) { short h = f2bf(u[j]); hi[j] = h; lo[j] = f2bf(u[j] - bf2f(h)); }
#pragma unroll
    for (int j = 0; j < 4; ++j) { short h = f2bf(v[j]); hi[4+j] = h; lo[4+j] = f2bf(v[j] - bf2f(h)); }
}
// guarded fast tanh: exact +-1.0 at saturation (R7-proven)
static __device__ __forceinline__ float fast_tanh(float x) {
    const float xc = fminf(15.0f, fmaxf(-15.0f, x));
    const float e = __expf(2.0f * xc);
    return (e - 1.0f) / (e + 1.0f);
}

// ---------------- Phase 0: colsum_c = sum_k Wh[k][c] -----------------------
__global__ __launch_bounds__(512, 1) void rnn_colsum(
    const float* __restrict__ weight, float* __restrict__ colsum)
{
    const int c = threadIdx.x;
    float s = 0.f;
    for (int k = 0; k < HDIM; ++k) s += weight[(size_t)(HDIM + k) * HDIM + c];
    colsum[c] = s;
}

// ---------------- Phase 1: xp(t) = input[t] @ Wx + bias -> out[t+1] --------
// (unchanged, proven ~1.0 ms)
__global__ __launch_bounds__(256, 2) void rnn_xproj(
    const float* __restrict__ input, const float* __restrict__ weight,
    const float* __restrict__ bias, float* __restrict__ out)
{
    __shared__ unsigned alds[64 * 128];
    __shared__ unsigned wlds[64 * 128];
    const int tid = threadIdx.x, lane = tid & 63, wv = tid >> 6;
    const int t = blockIdx.x >> 3, ct = blockIdx.x & 7;
    const int r16 = lane & 15, kg = lane >> 4, koff = kg * 8;
    const int colt = wv * 16 + r16;
    const int gcol = ct * 64 + colt;
    const float bv = bias[gcol];

    f32x4 acc[4][3];
#pragma unroll
    for (int mt = 0; mt < 4; ++mt) {
        acc[mt][0] = (f32x4){bv, bv, bv, bv};
        acc[mt][1] = (f32x4){0, 0, 0, 0};
        acc[mt][2] = (f32x4){0, 0, 0, 0};
    }
    for (int kq = 0; kq < 4; ++kq) {
        __syncthreads();
        for (int f = tid; f < 64 * 32; f += 256) {
            const int row = f >> 5, sg = f & 31;
            f32x4 v = *(const f32x4*)(input + (size_t)t * SLICE_T + row * HDIM + kq * 128 + sg * 4);
            const unsigned idx = ((unsigned)(row * 128 + sg * 4)) ^ (((unsigned)(row & 7)) << 2);
            u32x4 pk = {packsplit(v[0]), packsplit(v[1]), packsplit(v[2]), packsplit(v[3])};
            *(u32x4*)(&alds[idx]) = pk;
        }
        for (int f = tid; f < 128 * 16; f += 256) {
            const int k = f >> 4, cs = f & 15;
            f32x4 v = *(const f32x4*)(weight + (size_t)(kq * 128 + k) * HDIM + ct * 64 + cs * 4);
#pragma unroll
            for (int j = 0; j < 4; ++j) {
                const int c = cs * 4 + j;
                wlds[((unsigned)(c * 128 + k)) ^ (((unsigned)(c & 7)) << 2)] = packsplit(v[j]);
            }
        }
        __syncthreads();
#pragma unroll
        for (int c2 = 0; c2 < 4; ++c2) {
            const int kp = c2 * 32 + koff;
            const unsigned bi = (unsigned)(colt * 128 + kp), bx = ((unsigned)(colt & 7)) << 2;
            u32x4 qb0 = *(const u32x4*)&wlds[bi ^ bx];
            u32x4 qb1 = *(const u32x4*)&wlds[(bi + 4) ^ bx];
            short8 bhi, blo; build8v(qb0, qb1, bhi, blo);
#pragma unroll
            for (int mt = 0; mt < 4; ++mt) {
                const int row = mt * 16 + r16;
                const unsigned ai = (unsigned)(row * 128 + kp), ax = ((unsigned)(row & 7)) << 2;
                u32x4 qa0 = *(const u32x4*)&alds[ai ^ ax];
                u32x4 qa1 = *(const u32x4*)&alds[(ai + 4) ^ ax];
                short8 ahi, alo; build8v(qa0, qa1, ahi, alo);
                acc[mt][0] = MFMA16(ahi, bhi, acc[mt][0], 0, 0, 0);
                acc[mt][1] = MFMA16(alo, bhi, acc[mt][1], 0, 0, 0);
                acc[mt][2] = MFMA16(ahi, blo, acc[mt][2], 0, 0, 0);
            }
        }
    }
    float* ob = out + (size_t)(t + 1) * SLICE_T;
#pragma unroll
    for (int mt = 0; mt < 4; ++mt)
#pragma unroll
        for (int r = 0; r < 4; ++r)
            ob[(mt * 16 + kg * 4 + r) * HDIM + gcol] =
                acc[mt][0][r] + acc[mt][1][r] + acc[mt][2][r];
}

// ---------------- Phase 1b: saturation-persistence flags -------------------
// flagg[t][g] = 1 iff for ALL 8 rows b of group g and all 512 cols c:
//   xp_t[b][c] + colsum[c] > SAT_MARGIN
// => given h_t == +1^512, h_{t+1} == +1^512 EXACTLY (ref and ours).
__global__ __launch_bounds__(256, 2) void rnn_flags(
    const float* __restrict__ out, const float* __restrict__ colsum,
    unsigned* __restrict__ flagg)
{
    __shared__ float cs[HDIM];
    __shared__ int ok[8];
    const int tid = threadIdx.x, t = blockIdx.x;
    for (int i = tid; i < HDIM; i += 256) cs[i] = colsum[i];
    if (tid < 8) ok[tid] = 1;
    __syncthreads();
    const float* xp = out + (size_t)(t + 1) * SLICE_T;
    for (int i = tid; i < SLICE_T; i += 256) {
        const int c = i & 511;
        if (xp[i] + cs[c] <= SAT_MARGIN) ok[i >> 12] = 0;   // i>>12 = group
    }
    __syncthreads();
    if (tid < 8) flagg[(size_t)t * 8 + tid] = (unsigned)ok[tid];
}

// ---------------- Phase 2: persistent scan + saturation sprint -------------
// Base protocol = R6 (proven): 128 WGs = 8 groups x 16 slices, 2 waves; Wh
// fragments in LDS; exchange via RMW swaps into a 2-slot ring, drained
// (vmcnt0), then per-(g,s) monotone canary; consumer narrow-polls canaries.
// NEW: when consumed h_t == exactly +1^512 (packed word 0x00003F80) AND
// flagg[t][g], then h_{t+1} == +1^512 analytically -> write ones, skip all
// exchange/MFMA. All WGs of a group see identical h and flags -> lockstep
// branch decisions, no extra communication. Canary poll is value-based
// (cv >= t), so posting gaps during sprints are harmless.
__global__ __launch_bounds__(128, 1) void rnn_scan(
    const float* __restrict__ weight, const float* __restrict__ init_h,
    float* __restrict__ out, unsigned char* __restrict__ ws)
{
    __shared__ u32x4 whfA[16][2][64];
    __shared__ u32x4 whfB[16][2][64];
    unsigned* canary = (unsigned*)(ws + CAN_OFF);
    const unsigned* flagg = (const unsigned*)(ws + FLAG_OFF);
    unsigned* ring = (unsigned*)(ws + RING_OFF);

    const int tid = threadIdx.x, lane = tid & 63, wv = tid >> 6;
    const int g = blockIdx.x & 7, s = blockIdx.x >> 3;
    const int r16 = lane & 15, kg = lane >> 4, koff = kg * 8;
    const int gcol = s * 32 + wv * 16 + r16;
    const int brow = g * 8 + (r16 & 7);

    // one-time: Wh column-slice B-fragments into LDS
#pragma unroll
    for (int c = 0; c < 16; ++c) {
        unsigned p[8];
#pragma unroll
        for (int j = 0; j < 8; ++j)
            p[j] = packsplit(weight[(size_t)(HDIM + c * 32 + koff + j) * HDIM + gcol]);
        whfA[c][wv][lane] = (u32x4){p[0], p[1], p[2], p[3]};
        whfB[c][wv][lane] = (u32x4){p[4], p[5], p[6], p[7]};
    }
    for (int f = tid; f < 8 * 32; f += 128) {
        const int rr = f >> 5, cc = f & 31;
        out[(size_t)(g * 8 + rr) * HDIM + s * 32 + cc] = init_h[s * 32 + cc];
    }
    __syncthreads();

    bool h_ones = false;
    for (int t = 0; t < T_STEPS; ++t) {
        const bool has_next = (t + 1 < T_STEPS);

        // ---- saturated sprint: h_t==1 and flag says it persists ----
        if (h_ones && flagg[(size_t)t * 8 + g] != 0u) {
            float* ob = out + (size_t)(t + 1) * SLICE_T + (size_t)(g * 8) * HDIM + s * 32;
            for (int i = tid; i < 8 * 32; i += 128)
                __builtin_nontemporal_store(1.0f, ob + (size_t)(i >> 5) * HDIM + (i & 31));
            continue;   // no exchange, no MFMA; h stays all-ones
        }

        // xp(t) from out[t+1] (phase-1 data; this WG overwrites it below)
        const float* xpp = out + (size_t)(t + 1) * SLICE_T
                               + (size_t)(g * 8 + (kg & 1) * 4) * HDIM + gcol;
        const float xp0 = xpp[0 * HDIM], xp1 = xpp[1 * HDIM];
        const float xp2 = xpp[2 * HDIM], xp3 = xpp[3 * HDIM];

        f32x4 aA = {0, 0, 0, 0}, aB = {0, 0, 0, 0}, aC = {0, 0, 0, 0};

        if (h_ones) {
            // exit saturation: analytic all-ones A-fragments (lo == 0)
            short8 onehi;
#pragma unroll
            for (int j = 0; j < 8; ++j) onehi[j] = (short)0x3F80;
#pragma unroll
            for (int c = 0; c < 16; ++c) {
                short8 bhi, blo; build8v(whfA[c][wv][lane], whfB[c][wv][lane], bhi, blo);
                aA = MFMA16(onehi, bhi, aA, 0, 0, 0);
                aC = MFMA16(onehi, blo, aC, 0, 0, 0);
            }
            h_ones = false;
        } else if (t == 0) {
#pragma unroll
            for (int c = 0; c < 16; ++c) {
                f32x4 u = *(const f32x4*)(init_h + c * 32 + koff);
                f32x4 v = *(const f32x4*)(init_h + c * 32 + koff + 4);
                short8 ahi, alo; split8v(u, v, ahi, alo);
                short8 bhi, blo; build8v(whfA[c][wv][lane], whfB[c][wv][lane], bhi, blo);
                aA = MFMA16(ahi, bhi, aA, 0, 0, 0);
                aB = MFMA16(alo, bhi, aB, 0, 0, 0);
                aC = MFMA16(ahi, blo, aC, 0, 0, 0);
            }
        } else {
            // R6 narrow canary poll (bounded, dead-mode abort)
            int to = 0;
            {
                if (wv == 0) {
                    unsigned it = 0;
                    for (;;) {
                        unsigned cv = 0xffffffffu;
                        if (lane < NSLICE) cv = ALOAD(&canary[(g * NSLICE + lane) * 32]);
                        if (__all((int)(cv >= (unsigned)t))) break;
                        if (++it > SPIN_CAP) { to = 1; break; }
                    }
                }
                if (__syncthreads_count(to)) return;
            }
            const unsigned* rb = ring + (t & 1) * SLICE_T + brow * HDIM;
            unsigned long long q[16][4];
#pragma unroll
            for (int c = 0; c < 16; ++c) {
                const unsigned* p = rb + c * 32 + koff;
                q[c][0] = ALOAD((const unsigned long long*)(p + 0));
                q[c][1] = ALOAD((const unsigned long long*)(p + 2));
                q[c][2] = ALOAD((const unsigned long long*)(p + 4));
                q[c][3] = ALOAD((const unsigned long long*)(p + 6));
            }
            // saturation detect: every packed word == packsplit(1.0f)
            const unsigned long long OW2 = 0x00003F8000003F80ull;
            unsigned long long dif = 0;
#pragma unroll
            for (int c = 0; c < 16; ++c)
                dif |= (q[c][0] ^ OW2) | (q[c][1] ^ OW2) | (q[c][2] ^ OW2) | (q[c][3] ^ OW2);
            const bool sat = __all((int)(dif == 0ull));
            if (sat && flagg[(size_t)t * 8 + g] != 0u) {
                // enter sprint: h_{t+1} == all-ones; peers reach the same
                // conclusion from identical data -> nobody polls, nobody posts
                float* ob = out + (size_t)(t + 1) * SLICE_T + (size_t)(g * 8) * HDIM + s * 32;
                for (int i = tid; i < 8 * 32; i += 128)
                    __builtin_nontemporal_store(1.0f, ob + (size_t)(i >> 5) * HDIM + (i & 31));
                h_ones = true;
                continue;
            }
            // normal consume
#pragma unroll
            for (int c = 0; c < 16; ++c) {
                S8U hh, hl;
                unpack2w((unsigned)q[c][0], (unsigned)(q[c][0] >> 32), hh.u[0], hl.u[0]);
                unpack2w((unsigned)q[c][1], (unsigned)(q[c][1] >> 32), hh.u[1], hl.u[1]);
                unpack2w((unsigned)q[c][2], (unsigned)(q[c][2] >> 32), hh.u[2], hl.u[2]);
                unpack2w((unsigned)q[c][3], (unsigned)(q[c][3] >> 32), hh.u[3], hl.u[3]);
                short8 bhi, blo; build8v(whfA[c][wv][lane], whfB[c][wv][lane], bhi, blo);
                aA = MFMA16(hh.s8, bhi, aA, 0, 0, 0);
                aB = MFMA16(hl.s8, bhi, aB, 0, 0, 0);
                aC = MFMA16(hh.s8, blo, aC, 0, 0, 0);
            }
        }

        const float hn0 = fast_tanh(aA[0] + aB[0] + aC[0] + xp0);
        const float hn1 = fast_tanh(aA[1] + aB[1] + aC[1] + xp1);
        const float hn2 = fast_tanh(aA[2] + aB[2] + aC[2] + xp2);
        const float hn3 = fast_tanh(aA[3] + aB[3] + aC[3] + xp3);

        // post h_{t+1}: RMW swaps -> drain -> barrier -> canary (R6-proven)
        if (kg < 2 && has_next) {
            unsigned* wsl = ring + ((t + 1) & 1) * SLICE_T
                                 + (size_t)(g * 8 + kg * 4) * HDIM + gcol;
            ASWAP(&wsl[0 * HDIM], packsplit(hn0));
            ASWAP(&wsl[1 * HDIM], packsplit(hn1));
            ASWAP(&wsl[2 * HDIM], packsplit(hn2));
            ASWAP(&wsl[3 * HDIM], packsplit(hn3));
        }
        asm volatile("s_waitcnt vmcnt(0)" ::: "memory");
        __syncthreads();
        if (tid == 0 && has_next)
            ASWAP(&canary[(g * NSLICE + s) * 32], (unsigned)(t + 1));

        // off the inter-WG critical path: f32 h to out[t+1]
        if (kg < 2) {
            float* op = out + (size_t)(t + 1) * SLICE_T
                            + (size_t)(g * 8 + kg * 4) * HDIM + gcol;
            __builtin_nontemporal_store(hn0, op + 0 * HDIM);
            __builtin_nontemporal_store(hn1, op + 1 * HDIM);
            __builtin_nontemporal_store(hn2, op + 2 * HDIM);
            __builtin_nontemporal_store(hn3, op + 3 * HDIM);
        }
    }
}

extern "C" void kernel_launch(void* const* d_in, const int* in_sizes, int n_in,
                              void* d_out, int out_size, void* d_ws, size_t ws_size,
                              hipStream_t stream) {
    const float* input  = (const float*)d_in[0];
    const float* weight = (const float*)d_in[1];
    const float* biasp  = (const float*)d_in[2];
    const float* inith  = (const float*)d_in[3];
    float* out = (float*)d_out;
    unsigned char* ws = (unsigned char*)d_ws;

    // re-zero canaries each call (graph-replay deterministic); colsum/flagg
    // fully rewritten below; ring is canary-gated.
    hipMemsetAsync(d_ws, 0, 16384, stream);

    rnn_colsum<<<dim3(1), dim3(512), 0, stream>>>(weight, (float*)(ws + COLSUM_OFF));
    rnn_xproj<<<dim3(T_STEPS * 8), dim3(256), 0, stream>>>(input, weight, biasp, out);
    rnn_flags<<<dim3(T_STEPS), dim3(256), 0, stream>>>(
        out, (const float*)(ws + COLSUM_OFF), (unsigned*)(ws + FLAG_OFF));
    rnn_scan<<<dim3(NGROUP * NSLICE), dim3(128), 0, stream>>>(
        weight, inith, out, ws);
}

// Round 13
// 11689.700 us; speedup vs baseline: 4.5455x; 1.1916x over previous
//
#include <hip/hip_runtime.h>
#include <hip/hip_bf16.h>

typedef __attribute__((ext_vector_type(8))) short short8;
typedef __attribute__((ext_vector_type(4))) float f32x4;
typedef __attribute__((ext_vector_type(4))) unsigned u32x4;

#define T_STEPS 2048
#define HDIM 512
#define SLICE_T (64 * 512)      // elems per time slice
#define NGROUP 8                // batch groups (8 rows each)
#define NSLICE 16               // col slices (32 cols each)
#define CAN_OFF 0               // canaries: [128] 128B lines (16 KB)
#define COLSUM_OFF  16384       // colsum  f32[512]
#define COLSUM1_OFF 18432       // colsum1 f32[512] (h0-weighted)
#define AFLAG_OFF   20480       // allflagg u32[8]
#define CERT_OFF    20608       // cert u32[8]
#define RING_OFF 131072         // ring [2][64][512] packed u32 (256 KB)
#define SPIN_CAP 200000         // bounded spin; dead-mode, no hang
#define SAT_MARGIN 10.0f        // > both tanh==1.0f cutoffs (9.01 / 8.7) + skew

#define MFMA16 __builtin_amdgcn_mfma_f32_16x16x32_bf16
#define ALOAD(p)   __hip_atomic_load((p), __ATOMIC_RELAXED, __HIP_MEMORY_SCOPE_AGENT)
#define ASWAP(p,v) (void)__hip_atomic_exchange((p), (v), __ATOMIC_RELAXED, __HIP_MEMORY_SCOPE_AGENT)

static __device__ __forceinline__ short f2bf(float f) {
    __hip_bfloat16 h = __float2bfloat16(f);
    return __builtin_bit_cast(short, h);
}
static __device__ __forceinline__ float bf2f(short s) {
    unsigned u = ((unsigned)(unsigned short)s) << 16;
    return __builtin_bit_cast(float, u);
}
static __device__ __forceinline__ unsigned packsplit(float f) {
    short hi = f2bf(f);
    short lo = f2bf(f - bf2f(hi));
    return (unsigned)(unsigned short)hi | ((unsigned)(unsigned short)lo << 16);
}
static __device__ __forceinline__ void unpack2w(unsigned p0, unsigned p1,
                                                unsigned& hw, unsigned& lw) {
    hw = __builtin_amdgcn_perm(p1, p0, 0x05040100u);
    lw = __builtin_amdgcn_perm(p1, p0, 0x07060302u);
}
union S8U { short8 s8; unsigned u[4]; };
static __device__ __forceinline__ void build8v(u32x4 a, u32x4 b, short8& hi, short8& lo) {
    S8U H, L;
    unpack2w(a[0], a[1], H.u[0], L.u[0]);
    unpack2w(a[2], a[3], H.u[1], L.u[1]);
    unpack2w(b[0], b[1], H.u[2], L.u[2]);
    unpack2w(b[2], b[3], H.u[3], L.u[3]);
    hi = H.s8; lo = L.s8;
}
static __device__ __forceinline__ void split8v(f32x4 u, f32x4 v, short8& hi, short8& lo) {
#pragma unroll
    for (int j = 0; j < 4; ++j) { short h = f2bf(u[j]); hi[j] = h; lo[j] = f2bf(u[j] - bf2f(h)); }
#pragma unroll
    for (int j = 0; j < 4; ++j) { short h = f2bf(v[j]); hi[4+j] = h; lo[4+j] = f2bf(v[j] - bf2f(h)); }
}
static __device__ __forceinline__ float fast_tanh(float x) {
    const float xc = fminf(15.0f, fmaxf(-15.0f, x));
    const float e = __expf(2.0f * xc);
    return (e - 1.0f) / (e + 1.0f);
}

// ------- Phase 0: colsum, colsum1 (= h0@Wh per col), init allflagg --------
__global__ __launch_bounds__(512, 1) void rnn_colsum(
    const float* __restrict__ weight, const float* __restrict__ init_h,
    float* __restrict__ colsum, float* __restrict__ colsum1,
    unsigned* __restrict__ allflagg)
{
    const int c = threadIdx.x;
    float s = 0.f, s1 = 0.f;
    for (int k = 0; k < HDIM; ++k) {
        const float w = weight[(size_t)(HDIM + k) * HDIM + c];
        s += w; s1 += init_h[k] * w;
    }
    colsum[c] = s; colsum1[c] = s1;
    if (c < NGROUP) allflagg[c] = 1u;
}

// ------- Phase 1: xp(t) = input[t] @ Wx + bias -> out[t+1] (proven) -------
__global__ __launch_bounds__(256, 2) void rnn_xproj(
    const float* __restrict__ input, const float* __restrict__ weight,
    const float* __restrict__ bias, float* __restrict__ out)
{
    __shared__ unsigned alds[64 * 128];
    __shared__ unsigned wlds[64 * 128];
    const int tid = threadIdx.x, lane = tid & 63, wv = tid >> 6;
    const int t = blockIdx.x >> 3, ct = blockIdx.x & 7;
    const int r16 = lane & 15, kg = lane >> 4, koff = kg * 8;
    const int colt = wv * 16 + r16;
    const int gcol = ct * 64 + colt;
    const float bv = bias[gcol];

    f32x4 acc[4][3];
#pragma unroll
    for (int mt = 0; mt < 4; ++mt) {
        acc[mt][0] = (f32x4){bv, bv, bv, bv};
        acc[mt][1] = (f32x4){0, 0, 0, 0};
        acc[mt][2] = (f32x4){0, 0, 0, 0};
    }
    for (int kq = 0; kq < 4; ++kq) {
        __syncthreads();
        for (int f = tid; f < 64 * 32; f += 256) {
            const int row = f >> 5, sg = f & 31;
            f32x4 v = *(const f32x4*)(input + (size_t)t * SLICE_T + row * HDIM + kq * 128 + sg * 4);
            const unsigned idx = ((unsigned)(row * 128 + sg * 4)) ^ (((unsigned)(row & 7)) << 2);
            u32x4 pk = {packsplit(v[0]), packsplit(v[1]), packsplit(v[2]), packsplit(v[3])};
            *(u32x4*)(&alds[idx]) = pk;
        }
        for (int f = tid; f < 128 * 16; f += 256) {
            const int k = f >> 4, cs = f & 15;
            f32x4 v = *(const f32x4*)(weight + (size_t)(kq * 128 + k) * HDIM + ct * 64 + cs * 4);
#pragma unroll
            for (int j = 0; j < 4; ++j) {
                const int c = cs * 4 + j;
                wlds[((unsigned)(c * 128 + k)) ^ (((unsigned)(c & 7)) << 2)] = packsplit(v[j]);
            }
        }
        __syncthreads();
#pragma unroll
        for (int c2 = 0; c2 < 4; ++c2) {
            const int kp = c2 * 32 + koff;
            const unsigned bi = (unsigned)(colt * 128 + kp), bx = ((unsigned)(colt & 7)) << 2;
            u32x4 qb0 = *(const u32x4*)&wlds[bi ^ bx];
            u32x4 qb1 = *(const u32x4*)&wlds[(bi + 4) ^ bx];
            short8 bhi, blo; build8v(qb0, qb1, bhi, blo);
#pragma unroll
            for (int mt = 0; mt < 4; ++mt) {
                const int row = mt * 16 + r16;
                const unsigned ai = (unsigned)(row * 128 + kp), ax = ((unsigned)(row & 7)) << 2;
                u32x4 qa0 = *(const u32x4*)&alds[ai ^ ax];
                u32x4 qa1 = *(const u32x4*)&alds[(ai + 4) ^ ax];
                short8 ahi, alo; build8v(qa0, qa1, ahi, alo);
                acc[mt][0] = MFMA16(ahi, bhi, acc[mt][0], 0, 0, 0);
                acc[mt][1] = MFMA16(alo, bhi, acc[mt][1], 0, 0, 0);
                acc[mt][2] = MFMA16(ahi, blo, acc[mt][2], 0, 0, 0);
            }
        }
    }
    float* ob = out + (size_t)(t + 1) * SLICE_T;
#pragma unroll
    for (int mt = 0; mt < 4; ++mt)
#pragma unroll
        for (int r = 0; r < 4; ++r)
            ob[(mt * 16 + kg * 4 + r) * HDIM + gcol] =
                acc[mt][0][r] + acc[mt][1][r] + acc[mt][2][r];
}

// ------- Phase 1b: allflagg[g] &= AND_{t>=2} [min(xp_t + colsum) > 10] -----
__global__ __launch_bounds__(256, 2) void rnn_flags(
    const float* __restrict__ out, const float* __restrict__ colsum,
    unsigned* __restrict__ allflagg)
{
    __shared__ float cs[HDIM];
    __shared__ int ok[8];
    const int tid = threadIdx.x, t = blockIdx.x;
    if (t < 2) return;   // only t>=2 constrains the sprint
    for (int i = tid; i < HDIM; i += 256) cs[i] = colsum[i];
    if (tid < 8) ok[tid] = 1;
    __syncthreads();
    const float* xp = out + (size_t)(t + 1) * SLICE_T;
    for (int i = tid; i < SLICE_T; i += 256)
        if (xp[i] + cs[i & 511] <= SAT_MARGIN) ok[i >> 12] = 0;
    __syncthreads();
    if (tid < 8 && !ok[tid]) atomicAnd(&allflagg[tid], 0u);
}

// ------- Phase 1c: per-group certificate ----------------------------------
// h1 = tanh(xp0 + colsum1) (f32, exact enough: cushion 0.8 >> 0.1 skew);
// preact2 = xp1 + h1 @ Wh; cert[g] = (min preact2 > 10) && allflagg[g].
// cert => h_t == exactly 1.0f for ALL t>=2 in BOTH ref f32 and our bf16
// split arithmetic (both tanh cutoffs < 9.2; margins dominate all skews).
__global__ __launch_bounds__(256, 1) void rnn_cert(
    const float* __restrict__ weight, const float* __restrict__ out,
    const float* __restrict__ colsum1, const unsigned* __restrict__ allflagg,
    unsigned* __restrict__ cert)
{
    __shared__ float h1[8][HDIM];
    __shared__ float mins[256];
    const int g = blockIdx.x, tid = threadIdx.x;
    for (int i = tid; i < 8 * HDIM; i += 256) {
        const int b = i >> 9, c = i & 511;
        h1[b][c] = tanhf(out[(size_t)1 * SLICE_T + (size_t)(g * 8 + b) * HDIM + c] + colsum1[c]);
    }
    __syncthreads();
    float mn = 1e30f;
    for (int c = tid; c < HDIM; c += 256) {
        float acc[8] = {0, 0, 0, 0, 0, 0, 0, 0};
        for (int k = 0; k < HDIM; ++k) {
            const float w = weight[(size_t)(HDIM + k) * HDIM + c];
#pragma unroll
            for (int b = 0; b < 8; ++b) acc[b] += h1[b][k] * w;
        }
#pragma unroll
        for (int b = 0; b < 8; ++b)
            mn = fminf(mn, out[(size_t)2 * SLICE_T + (size_t)(g * 8 + b) * HDIM + c] + acc[b]);
    }
    mins[tid] = mn; __syncthreads();
    for (int w = 128; w > 0; w >>= 1) {
        if (tid < w) mins[tid] = fminf(mins[tid], mins[tid + w]);
        __syncthreads();
    }
    if (tid == 0) cert[g] = (mins[0] > SAT_MARGIN && allflagg[g] != 0u) ? 1u : 0u;
}

// ------- Phase 2: scan. cert groups: t=0 local + ones-blast, NO protocol. -
// uncert groups: proven R6 protocol (ring swaps + canaries).
__global__ __launch_bounds__(128, 1) void rnn_scan(
    const float* __restrict__ weight, const float* __restrict__ init_h,
    float* __restrict__ out, unsigned char* __restrict__ ws,
    const unsigned* __restrict__ cert)
{
    __shared__ u32x4 whfA[16][2][64];
    __shared__ u32x4 whfB[16][2][64];
    unsigned* canary = (unsigned*)(ws + CAN_OFF);
    unsigned* ring   = (unsigned*)(ws + RING_OFF);

    const int tid = threadIdx.x, lane = tid & 63, wv = tid >> 6;
    const int g = blockIdx.x & 7, s = blockIdx.x >> 3;
    const int r16 = lane & 15, kg = lane >> 4, koff = kg * 8;
    const int gcol = s * 32 + wv * 16 + r16;
    const int brow = g * 8 + (r16 & 7);
    const bool certg = cert[g] != 0u;

    // one-time: Wh column-slice B-fragments into LDS
#pragma unroll
    for (int c = 0; c < 16; ++c) {
        unsigned p[8];
#pragma unroll
        for (int j = 0; j < 8; ++j)
            p[j] = packsplit(weight[(size_t)(HDIM + c * 32 + koff + j) * HDIM + gcol]);
        whfA[c][wv][lane] = (u32x4){p[0], p[1], p[2], p[3]};
        whfB[c][wv][lane] = (u32x4){p[4], p[5], p[6], p[7]};
    }
    for (int f = tid; f < 8 * 32; f += 128) {
        const int rr = f >> 5, cc = f & 31;
        out[(size_t)(g * 8 + rr) * HDIM + s * 32 + cc] = init_h[s * 32 + cc];
    }
    __syncthreads();

    // ---- t = 0: local compute from init_h (no exchange needed) ----
    {
        const float* xpp = out + (size_t)1 * SLICE_T
                               + (size_t)(g * 8 + (kg & 1) * 4) * HDIM + gcol;
        const float xp0 = xpp[0 * HDIM], xp1 = xpp[1 * HDIM];
        const float xp2 = xpp[2 * HDIM], xp3 = xpp[3 * HDIM];
        f32x4 aA = {0, 0, 0, 0}, aB = {0, 0, 0, 0}, aC = {0, 0, 0, 0};
#pragma unroll
        for (int c = 0; c < 16; ++c) {
            f32x4 u = *(const f32x4*)(init_h + c * 32 + koff);
            f32x4 v = *(const f32x4*)(init_h + c * 32 + koff + 4);
            short8 ahi, alo; split8v(u, v, ahi, alo);
            short8 bhi, blo; build8v(whfA[c][wv][lane], whfB[c][wv][lane], bhi, blo);
            aA = MFMA16(ahi, bhi, aA, 0, 0, 0);
            aB = MFMA16(alo, bhi, aB, 0, 0, 0);
            aC = MFMA16(ahi, blo, aC, 0, 0, 0);
        }
        const float hn0 = fast_tanh(aA[0] + aB[0] + aC[0] + xp0);
        const float hn1 = fast_tanh(aA[1] + aB[1] + aC[1] + xp1);
        const float hn2 = fast_tanh(aA[2] + aB[2] + aC[2] + xp2);
        const float hn3 = fast_tanh(aA[3] + aB[3] + aC[3] + xp3);
        if (!certg && kg < 2) {
            unsigned* wsl = ring + 1 * SLICE_T + (size_t)(g * 8 + kg * 4) * HDIM + gcol;
            ASWAP(&wsl[0 * HDIM], packsplit(hn0));
            ASWAP(&wsl[1 * HDIM], packsplit(hn1));
            ASWAP(&wsl[2 * HDIM], packsplit(hn2));
            ASWAP(&wsl[3 * HDIM], packsplit(hn3));
        }
        if (!certg) {
            asm volatile("s_waitcnt vmcnt(0)" ::: "memory");
            __syncthreads();
            if (tid == 0) ASWAP(&canary[(g * NSLICE + s) * 32], 1u);
        }
        if (kg < 2) {
            float* op = out + (size_t)1 * SLICE_T + (size_t)(g * 8 + kg * 4) * HDIM + gcol;
            __builtin_nontemporal_store(hn0, op + 0 * HDIM);
            __builtin_nontemporal_store(hn1, op + 1 * HDIM);
            __builtin_nontemporal_store(hn2, op + 2 * HDIM);
            __builtin_nontemporal_store(hn3, op + 3 * HDIM);
        }
    }

    if (certg) {
        // ---- certified: out[2..2048] == exactly 1.0 — pure NT streams ----
        const int idx = tid & 63, row = idx >> 3, c4 = idx & 7;
        const f32x4 ones = {1.f, 1.f, 1.f, 1.f};
        float* base = out + (size_t)(g * 8 + row) * HDIM + s * 32 + c4 * 4;
        for (int t2 = 2 + (tid >> 6); t2 <= T_STEPS; t2 += 2)
            __builtin_nontemporal_store(ones, (f32x4*)(base + (size_t)t2 * SLICE_T));
        return;
    }

    // ---- uncertified: proven R6 protocol, t = 1..2047 ----
    for (int t = 1; t < T_STEPS; ++t) {
        const bool has_next = (t + 1 < T_STEPS);
        const float* xpp = out + (size_t)(t + 1) * SLICE_T
                               + (size_t)(g * 8 + (kg & 1) * 4) * HDIM + gcol;
        const float xp0 = xpp[0 * HDIM], xp1 = xpp[1 * HDIM];
        const float xp2 = xpp[2 * HDIM], xp3 = xpp[3 * HDIM];

        int to = 0;
        if (wv == 0) {
            unsigned it = 0;
            for (;;) {
                unsigned cv = 0xffffffffu;
                if (lane < NSLICE) cv = ALOAD(&canary[(g * NSLICE + lane) * 32]);
                if (__all((int)(cv >= (unsigned)t))) break;
                if (++it > SPIN_CAP) { to = 1; break; }
            }
        }
        if (__syncthreads_count(to)) return;   // hang-proof abort

        const unsigned* rb = ring + (t & 1) * SLICE_T + brow * HDIM;
        f32x4 aA = {0, 0, 0, 0}, aB = {0, 0, 0, 0}, aC = {0, 0, 0, 0};
#pragma unroll
        for (int c = 0; c < 16; ++c) {
            const unsigned* p = rb + c * 32 + koff;
            unsigned long long q0 = ALOAD((const unsigned long long*)(p + 0));
            unsigned long long q1 = ALOAD((const unsigned long long*)(p + 2));
            unsigned long long q2 = ALOAD((const unsigned long long*)(p + 4));
            unsigned long long q3 = ALOAD((const unsigned long long*)(p + 6));
            S8U hh, hl;
            unpack2w((unsigned)q0, (unsigned)(q0 >> 32), hh.u[0], hl.u[0]);
            unpack2w((unsigned)q1, (unsigned)(q1 >> 32), hh.u[1], hl.u[1]);
            unpack2w((unsigned)q2, (unsigned)(q2 >> 32), hh.u[2], hl.u[2]);
            unpack2w((unsigned)q3, (unsigned)(q3 >> 32), hh.u[3], hl.u[3]);
            short8 bhi, blo; build8v(whfA[c][wv][lane], whfB[c][wv][lane], bhi, blo);
            aA = MFMA16(hh.s8, bhi, aA, 0, 0, 0);
            aB = MFMA16(hl.s8, bhi, aB, 0, 0, 0);
            aC = MFMA16(hh.s8, blo, aC, 0, 0, 0);
        }

        const float hn0 = fast_tanh(aA[0] + aB[0] + aC[0] + xp0);
        const float hn1 = fast_tanh(aA[1] + aB[1] + aC[1] + xp1);
        const float hn2 = fast_tanh(aA[2] + aB[2] + aC[2] + xp2);
        const float hn3 = fast_tanh(aA[3] + aB[3] + aC[3] + xp3);

        if (kg < 2 && has_next) {
            unsigned* wsl = ring + ((t + 1) & 1) * SLICE_T
                                 + (size_t)(g * 8 + kg * 4) * HDIM + gcol;
            ASWAP(&wsl[0 * HDIM], packsplit(hn0));
            ASWAP(&wsl[1 * HDIM], packsplit(hn1));
            ASWAP(&wsl[2 * HDIM], packsplit(hn2));
            ASWAP(&wsl[3 * HDIM], packsplit(hn3));
        }
        asm volatile("s_waitcnt vmcnt(0)" ::: "memory");
        __syncthreads();
        if (tid == 0 && has_next)
            ASWAP(&canary[(g * NSLICE + s) * 32], (unsigned)(t + 1));

        if (kg < 2) {
            float* op = out + (size_t)(t + 1) * SLICE_T
                            + (size_t)(g * 8 + kg * 4) * HDIM + gcol;
            __builtin_nontemporal_store(hn0, op + 0 * HDIM);
            __builtin_nontemporal_store(hn1, op + 1 * HDIM);
            __builtin_nontemporal_store(hn2, op + 2 * HDIM);
            __builtin_nontemporal_store(hn3, op + 3 * HDIM);
        }
    }
}

extern "C" void kernel_launch(void* const* d_in, const int* in_sizes, int n_in,
                              void* d_out, int out_size, void* d_ws, size_t ws_size,
                              hipStream_t stream) {
    const float* input  = (const float*)d_in[0];
    const float* weight = (const float*)d_in[1];
    const float* biasp  = (const float*)d_in[2];
    const float* inith  = (const float*)d_in[3];
    float* out = (float*)d_out;
    unsigned char* ws = (unsigned char*)d_ws;

    // re-zero canaries each call; everything else rewritten per call.
    hipMemsetAsync(d_ws, 0, 16384, stream);

    rnn_colsum<<<dim3(1), dim3(512), 0, stream>>>(
        weight, inith, (float*)(ws + COLSUM_OFF), (float*)(ws + COLSUM1_OFF),
        (unsigned*)(ws + AFLAG_OFF));
    rnn_xproj<<<dim3(T_STEPS * 8), dim3(256), 0, stream>>>(input, weight, biasp, out);
    rnn_flags<<<dim3(T_STEPS), dim3(256), 0, stream>>>(
        out, (const float*)(ws + COLSUM_OFF), (unsigned*)(ws + AFLAG_OFF));
    rnn_cert<<<dim3(NGROUP), dim3(256), 0, stream>>>(
        weight, out, (const float*)(ws + COLSUM1_OFF),
        (const unsigned*)(ws + AFLAG_OFF), (unsigned*)(ws + CERT_OFF));
    rnn_scan<<<dim3(NGROUP * NSLICE), dim3(128), 0, stream>>>(
        weight, inith, out, ws, (const unsigned*)(ws + CERT_OFF));
}